// Round 1
// baseline (229.858 us; speedup 1.0000x reference)
//
#include <hip/hip_runtime.h>

#define BB 4
#define CCH 384
#define HH 56
#define WWD 56
#define HW (HH*WWD)     // 3136
#define KKK 5
#define SSS 7
#define S2 49           // S*S
#define D2 192          // C/2
#define K2 25           // K*K

// ---------------- Kernel 1: adaptive avg pool ctx -> ctx_p (B,C,7,7) ----------
__global__ __launch_bounds__(256) void pool_k(const float* __restrict__ ctx,
                                              float* __restrict__ ctx_p) {
    __shared__ float rowsum[392];
    int bc = blockIdx.x;                      // b*C + c
    const float* img = ctx + (size_t)bc * HW;
    for (int t = threadIdx.x; t < 392; t += 256) {
        int h = t / 7, bx = t % 7;
        const float* p = img + h * WWD + bx * 8;
        float s = 0.f;
#pragma unroll
        for (int i = 0; i < 8; i++) s += p[i];
        rowsum[t] = s;
    }
    __syncthreads();
    if (threadIdx.x < 49) {
        int by = threadIdx.x / 7, bx = threadIdx.x % 7;
        float s = 0.f;
#pragma unroll
        for (int r = 0; r < 8; r++) s += rowsum[(by * 8 + r) * 7 + bx];
        ctx_p[(size_t)bc * S2 + threadIdx.x] = s * (1.f / 64.f);
    }
}

// ---------------- Kernel 2: kf[b,d,s] = sum_c Wk[d,c] * ctx_p[b,c,s] ----------
__global__ __launch_bounds__(256) void kf_k(const float* __restrict__ Wk,
                                            const float* __restrict__ ctx_p,
                                            float* __restrict__ kf) {
    int idx = blockIdx.x * 256 + threadIdx.x;
    if (idx >= BB * D2 * S2) return;
    int s = idx % S2;
    int d = (idx / S2) % D2;
    int b = idx / (S2 * D2);
    const float* wrow = Wk + (size_t)d * CCH;
    const float* cp   = ctx_p + (size_t)b * CCH * S2 + s;
    float acc = 0.f;
#pragma unroll 4
    for (int c = 0; c < CCH; c++) acc += wrow[c] * cp[(size_t)c * S2];
    kf[idx] = acc;
}

// ---------------- Kernel 3: M[b,c,s] = sum_d Wq[d,c] * kf[b,d,s] -------------
__global__ __launch_bounds__(256) void m_k(const float* __restrict__ Wq,
                                           const float* __restrict__ kf,
                                           float* __restrict__ M) {
    int idx = blockIdx.x * 256 + threadIdx.x;
    if (idx >= BB * CCH * S2) return;
    int s = idx % S2;
    int c = (idx / S2) % CCH;
    int b = idx / (S2 * CCH);
    const float* kfb = kf + (size_t)b * D2 * S2 + s;
    float acc = 0.f;
#pragma unroll 4
    for (int d = 0; d < D2; d++) acc += Wq[(size_t)d * CCH + c] * kfb[(size_t)d * S2];
    M[idx] = acc;
}

// ------- Kernel 4: scores = x^T M, softmax over 49, dyn = Wwd * A ------------
// block = 256 threads = 64 pixels x 4 channel-groups; grid = B*49
__global__ __launch_bounds__(256) void attn_k(const float* __restrict__ x,
                                              const float* __restrict__ M,
                                              const float* __restrict__ Wwd,
                                              float* __restrict__ dyn) {
    __shared__ float xs[32][64];      // x chunk: 32 channels x 64 pixels
    __shared__ float Ms[32 * 49];     // M chunk
    __shared__ float sc[64][51];      // scores (pad 51: stride coprime w/ 32 banks)
    __shared__ float wl[K2 * 49];     // Wwd
    int b  = blockIdx.x / 49;
    int n0 = (blockIdx.x % 49) * 64;
    int p  = threadIdx.x & 63;        // pixel within block (== lane)
    int g  = threadIdx.x >> 6;        // s-group 0..3 (== wave id)
    const int nj = (g == 0) ? 13 : 12;
    float acc[13];
#pragma unroll
    for (int j = 0; j < 13; j++) acc[j] = 0.f;
    const float* xb = x + (size_t)b * CCH * HW + n0;
    const float* Mb = M + (size_t)b * CCH * S2;

    for (int c0 = 0; c0 < CCH; c0 += 32) {
        for (int i = threadIdx.x; i < 32 * 49; i += 256) Ms[i] = Mb[c0 * S2 + i];
        for (int i = threadIdx.x; i < 32 * 64; i += 256) {
            int cc = i >> 6, pp = i & 63;
            xs[cc][pp] = xb[(size_t)(c0 + cc) * HW + pp];
        }
        __syncthreads();
        for (int cc = 0; cc < 32; cc++) {
            float xv = xs[cc][p];
            const float* mr = &Ms[cc * 49 + g];
#pragma unroll
            for (int j = 0; j < 13; j++)
                if (j < nj) acc[j] += xv * mr[4 * j];   // LDS broadcast (wave-uniform)
        }
        __syncthreads();
    }
    for (int j = 0; j < nj; j++) sc[p][g + 4 * j] = acc[j];
    __syncthreads();

    // softmax (wave 0) + Wwd staging (waves 1-3), overlapped
    if (threadIdx.x < 64) {
        float m = -1e30f;
#pragma unroll
        for (int s = 0; s < 49; s++) m = fmaxf(m, sc[threadIdx.x][s]);
        float den = 0.f;
#pragma unroll
        for (int s = 0; s < 49; s++) {
            float e = __expf(sc[threadIdx.x][s] - m);
            sc[threadIdx.x][s] = e;
            den += e;
        }
        float inv = 1.f / den;
#pragma unroll
        for (int s = 0; s < 49; s++) sc[threadIdx.x][s] *= inv;
    } else {
        for (int i = threadIdx.x - 64; i < K2 * 49; i += 192) wl[i] = Wwd[i];
    }
    __syncthreads();

    float* dynb = dyn + (size_t)b * K2 * HW + n0;
    for (int o = threadIdx.x; o < 64 * K2; o += 256) {
        int j = o >> 6, pp = o & 63;
        const float* wr = &wl[j * 49];
        float a = 0.f;
#pragma unroll
        for (int s = 0; s < 49; s++) a += wr[s] * sc[pp][s];
        dynb[(size_t)j * HW + pp] = a;
    }
}

// -------- Kernel 5: out[b,c,h,w] = sum_j x_pad[..h+dy..w+dx] * dyn[b,j,h,w] --
// block = 448 threads = one 8-row stripe (8*56 px); 8 channels per block
__global__ __launch_bounds__(448) void out_k(const float* __restrict__ x,
                                             const float* __restrict__ dyn,
                                             float* __restrict__ out) {
    __shared__ float xt[8][12][60];   // 8 ch, 8+4 rows, 56+4 cols halo tile
    int blk    = blockIdx.x;
    int stripe = blk % 7;
    int cg     = (blk / 7) % 48;
    int b      = blk / (7 * 48);
    int h0 = stripe * 8;
    int c0 = cg * 8;
    const float* xb = x + ((size_t)(b * CCH + c0)) * HW;

    for (int i = threadIdx.x; i < 8 * 12 * 60; i += 448) {
        int cc  = i / 720;
        int rem = i % 720;
        int r   = rem / 60;
        int col = rem % 60;
        int h = h0 - 2 + r;
        int w = col - 2;
        float v = 0.f;
        if (h >= 0 && h < HH && w >= 0 && w < WWD)
            v = xb[(size_t)cc * HW + h * WWD + w];
        xt[cc][r][col] = v;
    }

    int hh = threadIdx.x / WWD;       // 0..7
    int ww = threadIdx.x % WWD;
    int h  = h0 + hh;
    int n  = h * WWD + ww;
    float dv[K2];
    const float* db = dyn + (size_t)b * K2 * HW + n;
#pragma unroll
    for (int j = 0; j < K2; j++) dv[j] = db[(size_t)j * HW];
    __syncthreads();

    float* ob = out + ((size_t)(b * CCH + c0)) * HW + n;
#pragma unroll
    for (int cc = 0; cc < 8; cc++) {
        float a = 0.f;
#pragma unroll
        for (int ky = 0; ky < KKK; ky++)
#pragma unroll
            for (int kx = 0; kx < KKK; kx++)
                a += xt[cc][hh + ky][ww + kx] * dv[ky * 5 + kx];
        ob[(size_t)cc * HW] = a;
    }
}

extern "C" void kernel_launch(void* const* d_in, const int* in_sizes, int n_in,
                              void* d_out, int out_size, void* d_ws, size_t ws_size,
                              hipStream_t stream) {
    const float* x   = (const float*)d_in[0];
    const float* ctx = (const float*)d_in[1];
    const float* Wq  = (const float*)d_in[2];
    const float* Wk  = (const float*)d_in[3];
    const float* Wwd = (const float*)d_in[4];
    float* out = (float*)d_out;
    float* ws  = (float*)d_ws;

    float* ctx_p = ws;                    // B*C*49      = 75264
    float* kf    = ws + 75264;            // B*192*49    = 37632
    float* M     = ws + 112896;           // B*C*49      = 75264
    float* dyn   = ws + 188160;           // B*25*3136   = 313600  (total ~2.0 MB)

    pool_k<<<BB * CCH, 256, 0, stream>>>(ctx, ctx_p);
    kf_k<<<(BB * D2 * S2 + 255) / 256, 256, 0, stream>>>(Wk, ctx_p, kf);
    m_k<<<(BB * CCH * S2 + 255) / 256, 256, 0, stream>>>(Wq, kf, M);
    attn_k<<<BB * 49, 256, 0, stream>>>(x, M, Wwd, dyn);
    out_k<<<BB * 48 * 7, 448, 0, stream>>>(x, dyn, out);
}

// Round 2
// 181.379 us; speedup vs baseline: 1.2673x; 1.2673x over previous
//
#include <hip/hip_runtime.h>

#define BB 4
#define CCH 384
#define HH 56
#define WWD 56
#define HW 3136
#define KKK 5
#define S2 49
#define S2P 52          // padded leading dim for M / scores (13 aligned float4 quads)
#define D2 192
#define K2 25

// ---------------- Kernel 1: adaptive avg pool ctx -> ctx_p (B,C,49) ----------
__global__ __launch_bounds__(256) void pool_k(const float* __restrict__ ctx,
                                              float* __restrict__ ctx_p) {
    __shared__ float rowsum[392];
    int bc = blockIdx.x;
    const float* img = ctx + (size_t)bc * HW;
    for (int t = threadIdx.x; t < 392; t += 256) {
        int h = t / 7, bx = t % 7;
        const float* p = img + h * WWD + bx * 8;
        float s = 0.f;
#pragma unroll
        for (int i = 0; i < 8; i++) s += p[i];
        rowsum[t] = s;
    }
    __syncthreads();
    if (threadIdx.x < 49) {
        int by = threadIdx.x / 7, bx = threadIdx.x % 7;
        float s = 0.f;
#pragma unroll
        for (int r = 0; r < 8; r++) s += rowsum[(by * 8 + r) * 7 + bx];
        ctx_p[(size_t)bc * S2 + threadIdx.x] = s * (1.f / 64.f);
    }
}

// ---------------- Kernel 2: kf[b,d,s] = sum_c Wk[d,c] * ctx_p[b,c,s] ----------
__global__ __launch_bounds__(256) void kf_k(const float* __restrict__ Wk,
                                            const float* __restrict__ ctx_p,
                                            float* __restrict__ kf) {
    int idx = blockIdx.x * 256 + threadIdx.x;
    if (idx >= BB * D2 * S2) return;
    int s = idx % S2;
    int d = (idx / S2) % D2;
    int b = idx / (S2 * D2);
    const float* wrow = Wk + (size_t)d * CCH;
    const float* cp   = ctx_p + (size_t)b * CCH * S2 + s;
    float acc = 0.f;
#pragma unroll 4
    for (int c = 0; c < CCH; c++) acc += wrow[c] * cp[(size_t)c * S2];
    kf[idx] = acc;
}

// --------- Kernel 3: Mpad[b,c,s] = sum_d Wq[d,c]*kf[b,d,s], stride 52 --------
__global__ __launch_bounds__(256) void m_k(const float* __restrict__ Wq,
                                           const float* __restrict__ kf,
                                           float* __restrict__ M) {
    int idx = blockIdx.x * 256 + threadIdx.x;
    if (idx >= BB * CCH * S2P) return;
    int s = idx % S2P;
    int c = (idx / S2P) % CCH;
    int b = idx / (S2P * CCH);
    if (s >= S2) { M[idx] = 0.f; return; }
    const float* kfb = kf + (size_t)b * D2 * S2 + s;
    float acc = 0.f;
#pragma unroll 4
    for (int d = 0; d < D2; d++) acc += Wq[(size_t)d * CCH + c] * kfb[(size_t)d * S2];
    M[idx] = acc;
}

// ------- Kernel 4: scores = x^T M (split-K x8), softmax, dyn = Wwd * A -------
// 256 threads, 32 pixels/block, grid = B * 98
__global__ __launch_bounds__(256) void attn_k(const float* __restrict__ x,
                                              const float* __restrict__ M,
                                              const float* __restrict__ Wwd,
                                              float* __restrict__ dyn) {
    __shared__ __align__(16) float smem[3072 + 96 * S2P]; // xs[96*32] | Ms[96*52]; red aliases (needs 6656 <= 8064)
    __shared__ __align__(16) float sc[32 * S2P];
    __shared__ __align__(16) float wl[K2 * S2P];
    float* xs  = smem;
    float* Ms  = smem + 3072;
    float* red = smem;

    int b    = blockIdx.x / 98;
    int n0   = (blockIdx.x % 98) * 32;
    int t    = threadIdx.x;
    int cs   = t >> 5;        // channel slice 0..7 (48 ch each, strided by chunk)
    int w5   = t & 31;
    int pxg  = w5 & 7;        // pixel quad -> px 4*pxg..4*pxg+3
    int sg   = w5 >> 3;       // s-quad group 0..3; quads g = sg+4k, k=0..3, g<13

    float4 acc4[4][4];        // [k][j: s-within-quad] over 4 px components
#pragma unroll
    for (int k = 0; k < 4; k++)
#pragma unroll
        for (int j = 0; j < 4; j++) acc4[k][j] = make_float4(0.f, 0.f, 0.f, 0.f);

    const float* xb = x + (size_t)b * CCH * HW + n0;
    const float* Mb = M + (size_t)b * CCH * S2P;

    for (int ch = 0; ch < 4; ch++) {
        int c0 = ch * 96;
        for (int i = t; i < 96 * 32; i += 256) {
            int r = i >> 5, col = i & 31;
            xs[i] = xb[(size_t)(c0 + r) * HW + col];
        }
        for (int i = t; i < 96 * S2P; i += 256)
            Ms[i] = Mb[(size_t)c0 * S2P + i];
        __syncthreads();

        int rbase = 12 * cs;
#pragma unroll 4
        for (int m = 0; m < 12; m++) {
            int r = rbase + m;
            const float4 xv = *(const float4*)&xs[r * 32 + 4 * pxg];
#pragma unroll
            for (int k = 0; k < 4; k++) {
                int g = sg + 4 * k;
                if (g < 13) {
                    const float4 mv = *(const float4*)&Ms[r * S2P + 4 * g];
                    acc4[k][0].x += mv.x * xv.x; acc4[k][0].y += mv.x * xv.y;
                    acc4[k][0].z += mv.x * xv.z; acc4[k][0].w += mv.x * xv.w;
                    acc4[k][1].x += mv.y * xv.x; acc4[k][1].y += mv.y * xv.y;
                    acc4[k][1].z += mv.y * xv.z; acc4[k][1].w += mv.y * xv.w;
                    acc4[k][2].x += mv.z * xv.x; acc4[k][2].y += mv.z * xv.y;
                    acc4[k][2].z += mv.z * xv.z; acc4[k][2].w += mv.z * xv.w;
                    acc4[k][3].x += mv.w * xv.x; acc4[k][3].y += mv.w * xv.y;
                    acc4[k][3].z += mv.w * xv.z; acc4[k][3].w += mv.w * xv.w;
                }
            }
        }
        __syncthreads();
    }

    // pair-combine channel slices 2w,2w+1 (lanes l and l^32 of each wave)
#pragma unroll
    for (int k = 0; k < 4; k++)
#pragma unroll
        for (int j = 0; j < 4; j++) {
            acc4[k][j].x += __shfl_xor(acc4[k][j].x, 32);
            acc4[k][j].y += __shfl_xor(acc4[k][j].y, 32);
            acc4[k][j].z += __shfl_xor(acc4[k][j].z, 32);
            acc4[k][j].w += __shfl_xor(acc4[k][j].w, 32);
        }

    // lanes <32 of each wave write pair-partials to red[wave][px][s]
    if ((t & 63) < 32) {
        int wv = t >> 6;
        float* rb = red + (size_t)(wv * 32) * S2P;
#pragma unroll
        for (int k = 0; k < 4; k++) {
            int g = sg + 4 * k;
            if (g < 13) {
                *(float4*)&rb[(4 * pxg + 0) * S2P + 4 * g] =
                    make_float4(acc4[k][0].x, acc4[k][1].x, acc4[k][2].x, acc4[k][3].x);
                *(float4*)&rb[(4 * pxg + 1) * S2P + 4 * g] =
                    make_float4(acc4[k][0].y, acc4[k][1].y, acc4[k][2].y, acc4[k][3].y);
                *(float4*)&rb[(4 * pxg + 2) * S2P + 4 * g] =
                    make_float4(acc4[k][0].z, acc4[k][1].z, acc4[k][2].z, acc4[k][3].z);
                *(float4*)&rb[(4 * pxg + 3) * S2P + 4 * g] =
                    make_float4(acc4[k][0].w, acc4[k][1].w, acc4[k][2].w, acc4[k][3].w);
            }
        }
    }
    // stage Wwd (padded cols 49..51 = 0)
    for (int i = t; i < K2 * S2P; i += 256) {
        int j = i / S2P, s = i % S2P;
        wl[i] = (s < S2) ? Wwd[j * S2 + s] : 0.f;
    }
    __syncthreads();

    // final 4-way reduce -> sc
    for (int o = t; o < 32 * 13; o += 256) {
        int px = o / 13, q = o - px * 13;
        float4 s = make_float4(0.f, 0.f, 0.f, 0.f);
#pragma unroll
        for (int wv = 0; wv < 4; wv++) {
            float4 v = *(float4*)&red[(size_t)(wv * 32 + px) * S2P + 4 * q];
            s.x += v.x; s.y += v.y; s.z += v.z; s.w += v.w;
        }
        *(float4*)&sc[px * S2P + 4 * q] = s;
    }
    __syncthreads();

    // softmax: 8 lanes per pixel
    {
        int px = t >> 3, li = t & 7;
        float mx = -3.4e38f;
#pragma unroll
        for (int k = 0; k < 7; k++) { int s = li + 8 * k; if (s < S2) mx = fmaxf(mx, sc[px * S2P + s]); }
        mx = fmaxf(mx, __shfl_xor(mx, 1, 8));
        mx = fmaxf(mx, __shfl_xor(mx, 2, 8));
        mx = fmaxf(mx, __shfl_xor(mx, 4, 8));
        float e[7]; float sum = 0.f;
#pragma unroll
        for (int k = 0; k < 7; k++) {
            int s = li + 8 * k;
            if (s < S2) { e[k] = __expf(sc[px * S2P + s] - mx); sum += e[k]; }
        }
        sum += __shfl_xor(sum, 1, 8);
        sum += __shfl_xor(sum, 2, 8);
        sum += __shfl_xor(sum, 4, 8);
        float inv = 1.f / sum;
#pragma unroll
        for (int k = 0; k < 7; k++) {
            int s = li + 8 * k;
            if (s < S2) sc[px * S2P + s] = e[k] * inv;
        }
    }
    __syncthreads();

    // dyn[b, j, n0+px] = sum_s wl[j,s] * sc[px,s]
    float* dynb = dyn + (size_t)b * K2 * HW + n0;
    for (int o = t; o < 32 * K2; o += 256) {
        int j = o >> 5, px = o & 31;
        float a = 0.f;
#pragma unroll
        for (int q = 0; q < 13; q++) {
            float4 wv = *(float4*)&wl[j * S2P + 4 * q];
            float4 pv = *(float4*)&sc[px * S2P + 4 * q];
            a += wv.x * pv.x + wv.y * pv.y + wv.z * pv.z + wv.w * pv.w;
        }
        dynb[(size_t)j * HW + px] = a;
    }
}

// -------- Kernel 5: 5x5 dynamic stencil; 8 ch x 8-row stripe; 2 rows/thread --
__global__ __launch_bounds__(256) void out_k(const float* __restrict__ x,
                                             const float* __restrict__ dyn,
                                             float* __restrict__ out) {
    __shared__ float xt[8][12][60];
    int blk    = blockIdx.x;
    int stripe = blk % 7;
    int cg     = (blk / 7) % 48;
    int b      = blk / (7 * 48);
    int h0 = stripe * 8;
    int c0 = cg * 8;
    const float* xb = x + ((size_t)(b * CCH + c0)) * HW;

    for (int i = threadIdx.x; i < 8 * 12 * 60; i += 256) {
        int cc  = i / 720;
        int rem = i % 720;
        int r   = rem / 60;
        int col = rem % 60;
        int h = h0 - 2 + r;
        int w = col - 2;
        float v = 0.f;
        if (h >= 0 && h < HH && (unsigned)w < (unsigned)WWD)
            v = xb[(size_t)cc * HW + h * WWD + w];
        xt[cc][r][col] = v;
    }

    int t = threadIdx.x;
    bool act = t < 224;
    int w  = t % 56;
    int hp = t / 56;                 // 0..3 (rows 2hp, 2hp+1)
    int n  = (h0 + 2 * hp) * WWD + w;
    float dv0[K2], dv1[K2];
    if (act) {
        const float* db = dyn + (size_t)b * K2 * HW + n;
#pragma unroll
        for (int j = 0; j < K2; j++) {
            dv0[j] = db[(size_t)j * HW];
            dv1[j] = db[(size_t)j * HW + WWD];
        }
    }
    __syncthreads();
    if (!act) return;

    float* ob = out + ((size_t)(b * CCH + c0)) * HW + n;
#pragma unroll
    for (int cc = 0; cc < 8; cc++) {
        float a0 = 0.f, a1 = 0.f;
#pragma unroll
        for (int rr = 0; rr < 6; rr++) {
            int lr = 2 * hp + rr;
            float v0 = xt[cc][lr][w + 0];
            float v1 = xt[cc][lr][w + 1];
            float v2 = xt[cc][lr][w + 2];
            float v3 = xt[cc][lr][w + 3];
            float v4 = xt[cc][lr][w + 4];
            if (rr < 5) {
                int o5 = rr * 5;
                a0 += v0 * dv0[o5] + v1 * dv0[o5 + 1] + v2 * dv0[o5 + 2]
                    + v3 * dv0[o5 + 3] + v4 * dv0[o5 + 4];
            }
            if (rr >= 1) {
                int o5 = (rr - 1) * 5;
                a1 += v0 * dv1[o5] + v1 * dv1[o5 + 1] + v2 * dv1[o5 + 2]
                    + v3 * dv1[o5 + 3] + v4 * dv1[o5 + 4];
            }
        }
        ob[(size_t)cc * HW] = a0;
        ob[(size_t)cc * HW + WWD] = a1;
    }
}

extern "C" void kernel_launch(void* const* d_in, const int* in_sizes, int n_in,
                              void* d_out, int out_size, void* d_ws, size_t ws_size,
                              hipStream_t stream) {
    const float* x   = (const float*)d_in[0];
    const float* ctx = (const float*)d_in[1];
    const float* Wq  = (const float*)d_in[2];
    const float* Wk  = (const float*)d_in[3];
    const float* Wwd = (const float*)d_in[4];
    float* out = (float*)d_out;
    float* ws  = (float*)d_ws;

    // overlap-aware layout (floats): dyn reuses ctx_p/kf space (dead by then)
    float* ctx_p = ws;                 // [0, 75264)       B*C*49
    float* kf    = ws + 75264;         // [75264, 112896)  B*192*49
    float* dyn   = ws;                 // [0, 313600)      B*25*3136 (after kf/ctx_p dead)
    float* Mpad  = ws + 313600;        // [313600, 393472) B*384*52

    pool_k<<<BB * CCH, 256, 0, stream>>>(ctx, ctx_p);
    kf_k<<<(BB * D2 * S2 + 255) / 256, 256, 0, stream>>>(Wk, ctx_p, kf);
    m_k<<<(BB * CCH * S2P + 255) / 256, 256, 0, stream>>>(Wq, kf, Mpad);
    attn_k<<<BB * 98, 256, 0, stream>>>(x, Mpad, Wwd, dyn);
    out_k<<<BB * 48 * 7, 256, 0, stream>>>(x, dyn, out);
}